// Round 5
// baseline (116.176 us; speedup 1.0000x reference)
//
#include <hip/hip_runtime.h>
#include <hip/hip_bf16.h>

// out[b] = 0.1*log1p(1/S_b),  S_b = sum_k w_k * exp(-5*acos(ip_bk)^2)
// R5 (= R4 + compile fix): NO LDS, NO BARRIERS. B pre-swizzled into MFMA
// fragment order in global (L2/L1-hot, coalesced dwordx4); A register-resident
// (32 rows/wave); register double-buffered B; one shfl-reduce at the end.

typedef __attribute__((ext_vector_type(8))) short short8;   // 8 bf16
typedef __attribute__((ext_vector_type(4))) float f32x4;    // native vec4

#define KP 1024
#define DD 128

__device__ __forceinline__ unsigned int f2bf(float f) {
  unsigned int u = __float_as_uint(f);
  return (u + 0x7FFFu + ((u >> 16) & 1u)) >> 16;   // RNE fp32->bf16
}

// ---- prep: 32 blocks x 32 cols. Normalize mus cols, w=exp(-10a), and write
// bf16 B in fragment order: unit idx = j*512 + nt*256 + kkk*64 + q*16 + l15
// holding col = j*32+nt*16+l15, k = kkk*32+q*8 .. +8.
__global__ __launch_bounds__(256) void prep_kernel(
    const float* __restrict__ mus, const float* __restrict__ alphas,
    uint4* __restrict__ bsw, float* __restrict__ w) {
  __shared__ float psum[8][32];
  __shared__ float Tt[32][129];
  __shared__ float inv_s[32];
  const int t = threadIdx.x;
  const int k0 = blockIdx.x * 32;
  const int kk = t & 31, gg = t >> 5;
  float s = 0.0f;
  for (int i = 0; i < 16; ++i) {
    float v = mus[(gg * 16 + i) * KP + k0 + kk];
    s = fmaf(v, v, s);
  }
  psum[gg][kk] = s;
  __syncthreads();
  if (t < 32) {
    float tot = 0.0f;
    for (int j = 0; j < 8; ++j) tot += psum[j][t];
    inv_s[t] = rsqrtf(tot);
    w[k0 + t] = __expf(-10.0f * alphas[k0 + t]);
  }
  for (int i = 0; i < 16; ++i) {            // transpose 128x32 tile via LDS
    int e = i * 256 + t;
    Tt[e & 31][e >> 5] = mus[(e >> 5) * KP + k0 + (e & 31)];
  }
  __syncthreads();
  #pragma unroll
  for (int i = 0; i < 2; ++i) {             // 512 units/block, 16B writes
    int u = i * 256 + t;
    int c32 = u & 31, w0 = u >> 5;          // w0 = k/8 in [0,16)
    float inv = inv_s[c32];
    uint4 o;
    o.x = f2bf(Tt[c32][w0 * 8 + 0] * inv) | (f2bf(Tt[c32][w0 * 8 + 1] * inv) << 16);
    o.y = f2bf(Tt[c32][w0 * 8 + 2] * inv) | (f2bf(Tt[c32][w0 * 8 + 3] * inv) << 16);
    o.z = f2bf(Tt[c32][w0 * 8 + 4] * inv) | (f2bf(Tt[c32][w0 * 8 + 5] * inv) << 16);
    o.w = f2bf(Tt[c32][w0 * 8 + 6] * inv) | (f2bf(Tt[c32][w0 * 8 + 7] * inv) << 16);
    // nt=(c32>>4), kkk=(w0>>2), q=(w0&3), l15=(c32&15)
    int idx = blockIdx.x * 512 + ((c32 >> 4) << 8) + ((w0 >> 2) << 6) +
              ((w0 & 3) << 4) + (c32 & 15);
    bsw[idx] = o;
  }
}

// ---- main: 512 blocks x 256 thr (2 blocks/CU, 2 waves/SIMD). Wave owns 32
// rows; loops j=0..31 over 32-col groups; B fragments straight from global.
__global__ __launch_bounds__(256, 2) void main_kernel(
    const float* __restrict__ xs, const uint4* __restrict__ bsw,
    const float* __restrict__ w, float* __restrict__ out) {
  const int t = threadIdx.x;
  const int wv = t >> 6, ln = t & 63, q = ln >> 4, l15 = ln & 15;
  const int row0 = (blockIdx.x * 4 + wv) * 32;

  // A fragments (one-time): afr[mt][kkk] = xs[row0+mt*16+l15][kkk*32+q*8..+8]
  short8 afr[2][4];
  #pragma unroll
  for (int mt = 0; mt < 2; ++mt)
    #pragma unroll
    for (int kkk = 0; kkk < 4; ++kkk) {
      const f32x4* p = (const f32x4*)(xs +
          (size_t)(row0 + mt * 16 + l15) * DD + kkk * 32 + q * 8);
      f32x4 f0 = __builtin_nontemporal_load(p);        // keep B in L2
      f32x4 f1 = __builtin_nontemporal_load(p + 1);
      union { short8 s; uint4 u; } a;
      a.u.x = f2bf(f0.x) | (f2bf(f0.y) << 16);
      a.u.y = f2bf(f0.z) | (f2bf(f0.w) << 16);
      a.u.z = f2bf(f1.x) | (f2bf(f1.y) << 16);
      a.u.w = f2bf(f1.z) | (f2bf(f1.w) << 16);
      afr[mt][kkk] = a.s;
    }

  float sums[8];
  #pragma unroll
  for (int i = 0; i < 8; ++i) sums[i] = 0.0f;

  const uint4* bp = bsw + ln;

  short8 bA[2][4], bB[2][4];
  auto load_b = [&](short8 bf[2][4], int j) {
    #pragma unroll
    for (int nt = 0; nt < 2; ++nt)
      #pragma unroll
      for (int kkk = 0; kkk < 4; ++kkk) {
        union { short8 s; uint4 u; } tmp;
        tmp.u = bp[(j * 8 + nt * 4 + kkk) * 64];
        bf[nt][kkk] = tmp.s;
      }
  };
  auto compute = [&](short8 bf[2][4], int j) {
    float wn[2];
    wn[0] = w[j * 32 + l15];
    wn[1] = w[j * 32 + 16 + l15];
    f32x4 acc[2][2];
    #pragma unroll
    for (int mt = 0; mt < 2; ++mt)
      #pragma unroll
      for (int nt = 0; nt < 2; ++nt)
        acc[mt][nt] = (f32x4){0.f, 0.f, 0.f, 0.f};
    #pragma unroll
    for (int kkk = 0; kkk < 4; ++kkk)
      #pragma unroll
      for (int mt = 0; mt < 2; ++mt)
        #pragma unroll
        for (int nt = 0; nt < 2; ++nt)
          acc[mt][nt] = __builtin_amdgcn_mfma_f32_16x16x32_bf16(
              afr[mt][kkk], bf[nt][kkk], acc[mt][nt], 0, 0, 0);
    #pragma unroll
    for (int mt = 0; mt < 2; ++mt)
      #pragma unroll
      for (int nt = 0; nt < 2; ++nt)
        #pragma unroll
        for (int r = 0; r < 4; ++r) {
          float x = acc[mt][nt][r];
          float z = fmaxf(fmaf(x, -0.5f, 0.5f), 0.0f);   // (1-x)/2
          float h = fmaf(z, -3.6067376f, -2.3449500f);   // -28.8539*G(z)
          h = fmaf(z, h, -3.2975886f);
          h = fmaf(z, h, -5.1295823f);
          h = fmaf(z, h, -9.6179669f);
          h = fmaf(z, h, -28.8539008f);
          float e = __builtin_amdgcn_exp2f(z * h);
          sums[mt * 4 + r] = fmaf(e, wn[nt], sums[mt * 4 + r]);
        }
  };

  load_b(bA, 0);
  for (int j = 0; j < 32; j += 2) {
    load_b(bB, j + 1);
    compute(bA, j);
    load_b(bA, (j + 2 < 32) ? (j + 2) : 31);   // last one redundant, harmless
    compute(bB, j + 1);
  }

  // reduce over 16 col-lanes; lane l15==0 holds rows q*4+r (+mt*16)
  #pragma unroll
  for (int s2 = 1; s2 < 16; s2 <<= 1)
    #pragma unroll
    for (int r = 0; r < 8; ++r) sums[r] += __shfl_xor(sums[r], s2, 64);
  if (l15 == 0) {
    #pragma unroll
    for (int mt = 0; mt < 2; ++mt)
      #pragma unroll
      for (int r = 0; r < 4; ++r)
        out[row0 + mt * 16 + q * 4 + r] =
            0.1f * log1pf(1.0f / sums[mt * 4 + r]);
  }
}

extern "C" void kernel_launch(void* const* d_in, const int* in_sizes, int n_in,
                              void* d_out, int out_size, void* d_ws, size_t ws_size,
                              hipStream_t stream) {
  const float* xs     = (const float*)d_in[0];   // [65536,128]
  const float* mus    = (const float*)d_in[1];   // [128,1024]
  const float* alphas = (const float*)d_in[2];   // [1024]
  float* out = (float*)d_out;

  uint4* bsw = (uint4*)d_ws;                                   // 256 KiB
  float* w = (float*)((char*)d_ws + 16384 * sizeof(uint4));    // 4 KiB

  prep_kernel<<<KP / 32, 256, 0, stream>>>(mus, alphas, bsw, w);
  const int B = in_sizes[0] / DD;   // 65536
  main_kernel<<<B / 128, 256, 0, stream>>>(xs, bsw, w, out);
}